// Round 1
// baseline (146.468 us; speedup 1.0000x reference)
//
#include <hip/hip_runtime.h>
#include <math.h>

// LinearGating: B=4,S=4096,D=2048,E=64,K=2  -> N=16384 rows
// out layout (flat float32): [weights N*64][indices N*2 (as float)][logits N*64][probs N*64]

constexpr int NROWS = 16384;
constexpr int DDIM  = 2048;
constexpr int NE    = 64;
constexpr int BM    = 32;          // rows per block
constexpr int BK    = 64;          // k-tile
constexpr int NC    = 128;         // interleaved cols: per expert-pair {g0,g1,n0,n1}
constexpr int NKT   = DDIM / BK;   // 32
constexpr float NSCALE = 1.0f / (64.0f * 64.0f);

__device__ inline float softplus_f(float x) {
    // matches jax.nn.softplus: max(x,0) + log1p(exp(-|x|))
    return fmaxf(x, 0.0f) + log1pf(expf(-fabsf(x)));
}

__global__ __launch_bounds__(256, 2) void gating_kernel(
    const float* __restrict__ x, const float* __restrict__ Wg,
    const float* __restrict__ Wn, const float* __restrict__ noise,
    float* __restrict__ out_w, float* __restrict__ out_idx,
    float* __restrict__ out_logits, float* __restrict__ out_probs)
{
    __shared__ float smem[BM * BK + BK * NC];   // 2048 + 8192 floats = 40 KB
    float* xs = smem;              // [BM][BK]   stride 64
    float* ws = smem + BM * BK;    // [BK][NC]   stride 128

    const int tid  = threadIdx.x;
    const int row0 = blockIdx.x * BM;
    const int cg   = tid & 31;     // expert-pair group (experts 2cg, 2cg+1)
    const int rg   = tid >> 5;     // 0..7  (rows rg + 8*i)
    const int e0   = cg * 2;

    float acc[4][4];               // [row i][{gate e0, gate e0+1, noise e0, noise e0+1}]
    #pragma unroll
    for (int i = 0; i < 4; ++i)
        #pragma unroll
        for (int j = 0; j < 4; ++j) acc[i][j] = 0.0f;

    for (int kt = 0; kt < NKT; ++kt) {
        const int k0 = kt * BK;
        // ---- stage x tile: 32 rows x 64 k = 512 float4, 2 per thread ----
        #pragma unroll
        for (int j = 0; j < 2; ++j) {
            int idx = tid + 256 * j;
            int r = idx >> 4, kq = idx & 15;
            float4 v = *reinterpret_cast<const float4*>(
                &x[(size_t)(row0 + r) * DDIM + k0 + kq * 4]);
            *reinterpret_cast<float4*>(&xs[r * BK + kq * 4]) = v;
        }
        // ---- stage W tile: 64 k x 32 pairs, interleaved {g,g,n,n}, 8 per thread ----
        #pragma unroll
        for (int j = 0; j < 8; ++j) {
            int idx = tid + 256 * j;
            int kk = idx >> 5, c = idx & 31;
            float2 g2 = *reinterpret_cast<const float2*>(&Wg[(size_t)(k0 + kk) * NE + c * 2]);
            float2 n2 = *reinterpret_cast<const float2*>(&Wn[(size_t)(k0 + kk) * NE + c * 2]);
            float4 v = make_float4(g2.x, g2.y, n2.x, n2.y);
            *reinterpret_cast<float4*>(&ws[kk * NC + c * 4]) = v;
        }
        __syncthreads();
        // ---- compute: 16 sub-iters x (8 ds_read_b128 -> 64 FMA) ----
        #pragma unroll
        for (int kk4 = 0; kk4 < 16; ++kk4) {
            float4 a[4], b[4];
            #pragma unroll
            for (int i = 0; i < 4; ++i)
                a[i] = *reinterpret_cast<const float4*>(&xs[(rg + 8 * i) * BK + kk4 * 4]);
            #pragma unroll
            for (int j = 0; j < 4; ++j)
                b[j] = *reinterpret_cast<const float4*>(&ws[(kk4 * 4 + j) * NC + cg * 4]);
            #pragma unroll
            for (int i = 0; i < 4; ++i) {
                float ax[4] = {a[i].x, a[i].y, a[i].z, a[i].w};
                #pragma unroll
                for (int j = 0; j < 4; ++j) {
                    acc[i][0] = fmaf(ax[j], b[j].x, acc[i][0]);
                    acc[i][1] = fmaf(ax[j], b[j].y, acc[i][1]);
                    acc[i][2] = fmaf(ax[j], b[j].z, acc[i][2]);
                    acc[i][3] = fmaf(ax[j], b[j].w, acc[i][3]);
                }
            }
        }
        __syncthreads();
    }

    // ================= epilogue (LDS reused) =================
    float* lg   = smem;                  // [NE][33]  (stride 33: conflict-free both axes)
    float* sv0  = smem + NE * 33;        // per-row top1 value
    float* sise = sv0  + BM;             // 1/sum(exp)
    float* sw0  = sise + BM;             // weight at top1
    float* sw1  = sw0  + BM;             // weight at top2
    int*   si0  = (int*)(sw1 + BM);
    int*   si1  = si0 + BM;

    // step A: finalize logits (noise injection) for this thread's 2 experts x 4 rows
    #pragma unroll
    for (int i = 0; i < 4; ++i) {
        int r = rg + 8 * i;
        int n = row0 + r;
        float2 nz = *reinterpret_cast<const float2*>(&noise[(size_t)n * NE + e0]);
        float nstd0 = softplus_f(acc[i][2]) * NSCALE;
        float nstd1 = softplus_f(acc[i][3]) * NSCALE;
        float g0 = acc[i][0] + nz.x * nstd0;
        float g1 = acc[i][1] + nz.y * nstd1;
        lg[e0 * 33 + r]       = g0;
        lg[(e0 + 1) * 33 + r] = g1;
        *reinterpret_cast<float2*>(&out_logits[(size_t)n * NE + e0]) = make_float2(g0, g1);
    }
    __syncthreads();

    // step B: per-row top-2 + softmax denominator (32 lanes, conflict-free LDS)
    if (tid < BM) {
        int r = tid;
        float v0 = -INFINITY, v1 = -INFINITY;
        int i0 = 0, i1 = 0;
        for (int e = 0; e < NE; ++e) {
            float v = lg[e * 33 + r];
            if (v > v0) { v1 = v0; i1 = i0; v0 = v; i0 = e; }
            else if (v > v1) { v1 = v; i1 = e; }
        }
        float se = 0.0f;
        for (int e = 0; e < NE; ++e) se += expf(lg[e * 33 + r] - v0);
        float w1e = expf(v1 - v0);
        float s2  = 1.0f + w1e;           // exp(-1e9 - v0) == 0 for the 62 masked entries
        sv0[r]  = v0;
        sise[r] = 1.0f / se;
        sw0[r]  = 1.0f / s2;
        sw1[r]  = w1e / s2;
        si0[r]  = i0;
        si1[r]  = i1;
    }
    __syncthreads();

    // step C: coalesced writes of probs + weights
    #pragma unroll
    for (int j = 0; j < 8; ++j) {
        int idx = tid + 256 * j;
        int r = idx >> 6, e = idx & 63;
        int n = row0 + r;
        float g = lg[e * 33 + r];
        float p = expf(g - sv0[r]) * sise[r];
        float w = (e == si0[r]) ? sw0[r] : ((e == si1[r]) ? sw1[r] : 0.0f);
        out_probs[(size_t)n * NE + e] = p;
        out_w[(size_t)n * NE + e]     = w;
    }
    // step D: indices (as float values)
    if (tid < BM * 2) {
        int r = tid >> 1, j = tid & 1;
        int v = j ? si1[r] : si0[r];
        out_idx[(size_t)(row0 + r) * 2 + j] = (float)v;
    }
}

extern "C" void kernel_launch(void* const* d_in, const int* in_sizes, int n_in,
                              void* d_out, int out_size, void* d_ws, size_t ws_size,
                              hipStream_t stream) {
    (void)in_sizes; (void)n_in; (void)d_ws; (void)ws_size; (void)out_size;
    const float* x     = (const float*)d_in[0];
    const float* Wg    = (const float*)d_in[1];
    const float* Wn    = (const float*)d_in[2];
    const float* noise = (const float*)d_in[3];
    float* out        = (float*)d_out;
    float* out_w      = out;                                  // N*64
    float* out_idx    = out + (size_t)NROWS * NE;             // N*2
    float* out_logits = out_idx + (size_t)NROWS * 2;          // N*64
    float* out_probs  = out_logits + (size_t)NROWS * NE;      // N*64

    dim3 grid(NROWS / BM);   // 512 blocks
    gating_kernel<<<grid, 256, 0, stream>>>(x, Wg, Wn, noise,
                                            out_w, out_idx, out_logits, out_probs);
}